// Round 16
// baseline (219.467 us; speedup 1.0000x reference)
//
#include <hip/hip_runtime.h>

#define HD 64
#define ED 16

typedef __bf16 bf16x8 __attribute__((ext_vector_type(8)));
typedef float  f32x4  __attribute__((ext_vector_type(4)));
typedef unsigned int u32;
typedef unsigned long long u64;
typedef unsigned short u16;

static inline __device__ float bf2f(u16 u){
    union { u32 i; float f; } v; v.i = ((u32)u) << 16; return v.f;
}
static inline __device__ u16 f2bf(float f){
    union { u32 i; float f; } v; v.f = f;
    u32 r = v.i + 0x7FFF + ((v.i >> 16) & 1);
    return (u16)(r >> 16);
}
static inline __device__ u32 pk2(float a, float b){
    return (u32)f2bf(a) | ((u32)f2bf(b) << 16);
}

__global__ void k_zero2(int* a, int* b, int n){
    int i = blockIdx.x*blockDim.x + threadIdx.x;
    if(i < n){ a[i] = 0; b[i] = 0; }
}
__global__ void k_deg(const int* __restrict__ src, const int* __restrict__ dst, int E,
                      int* __restrict__ degs, int* __restrict__ degd){
    int e = blockIdx.x*blockDim.x + threadIdx.x;
    if(e < E){ atomicAdd(&degs[src[e]], 1); atomicAdd(&degd[dst[e]], 1); }
}

// single-block scan: deg_src -> rowptr/cursor ; deg_dst -> countsf = max(deg,1)
__global__ void k_scan(const int* __restrict__ degs, const int* __restrict__ degd, int N,
                       int* __restrict__ rowptr, int* __restrict__ cursor, float* __restrict__ countsf){
    __shared__ int part[1024];
    int tid = threadIdx.x;
    int PER = (N + 1023) >> 10;
    int base = tid * PER;
    int local[16];
    int s = 0;
    for(int j = 0; j < PER; j++){
        int idx = base + j;
        int v = (idx < N) ? degs[idx] : 0;
        local[j] = s; s += v;
    }
    part[tid] = s;
    __syncthreads();
    for(int off = 1; off < 1024; off <<= 1){
        int v = (tid >= off) ? part[tid - off] : 0;
        __syncthreads();
        part[tid] += v;
        __syncthreads();
    }
    int prev = (tid == 0) ? 0 : part[tid - 1];
    for(int j = 0; j < PER; j++){
        int idx = base + j;
        if(idx < N){
            int r = prev + local[j];
            rowptr[idx] = r; cursor[idx] = r;
            int dd = degd[idx];
            countsf[idx] = (dd > 0) ? (float)dd : 1.0f;
        }
    }
    if(tid == 1023) rowptr[N] = prev + s;
}

__global__ void k_fill(const int* __restrict__ src, int E, int* __restrict__ cursor, int* __restrict__ elist){
    int e = blockIdx.x*blockDim.x + threadIdx.x;
    if(e < E){ int p = atomicAdd(&cursor[src[e]], 1); elist[p] = e; }
}

// h1E[p] = bf16(relu(edge_attr[elist[p]] @ W1 + b1)) in CSR order; dstE[p] = dst[elist[p]]
__global__ void k_h1E(const float* __restrict__ ea, const float* __restrict__ W1,
                      const float* __restrict__ b1, const int* __restrict__ elist,
                      const int* __restrict__ dstarr, int E,
                      u16* __restrict__ h1E, int* __restrict__ dstE){
    __shared__ float s_ea[4][ED];
    __shared__ int s_e[4];
    int t = threadIdx.x;              // 256
    int o = t & 63, el = t >> 6;
    int p = blockIdx.x*4 + el;
    if(t < 4){
        int pp = blockIdx.x*4 + t;
        s_e[t] = (pp < E) ? elist[pp] : 0;
    }
    __syncthreads();
    if(t < 4*ED){
        int pe = t/ED;
        s_ea[pe][t%ED] = ea[(size_t)s_e[pe]*ED + t%ED];
    }
    __syncthreads();
    if(p < E){
        float acc = b1[o];
        #pragma unroll
        for(int k = 0; k < ED; k++) acc += s_ea[el][k] * W1[k*HD + o];
        h1E[(size_t)p*HD + o] = f2bf(acc > 0.f ? acc : 0.f);
        if(o == 0) dstE[p] = dstarr[s_e[el]];
    }
}

// merged one-time conversions: PT (from W2+b2), WihB, WhhB, WrB, Abf(from x)
#define SEG_PT   (65*HD*HD)          // 266240
#define SEG_WIH  (3*HD*HD)           // 12288
#define SEG_WHH  (3*HD*HD)
#define SEG_WR   (HD*HD)
__global__ void k_prep(const float* __restrict__ W2, const float* __restrict__ b2,
                       const float* __restrict__ w_ih, const float* __restrict__ w_hh,
                       const float* __restrict__ Wroot, const float* __restrict__ x,
                       u16* __restrict__ PT, u16* __restrict__ WihB, u16* __restrict__ WhhB,
                       u16* __restrict__ WrB, u16* __restrict__ Abf, int nx){
    int idx = blockIdx.x*blockDim.x + threadIdx.x;
    if(idx < SEG_PT){
        int c = idx / HD, i = idx % HD;
        int kc = c >> 6, o = c & 63;
        float v = (kc < HD) ? W2[(size_t)kc*(HD*HD) + i*HD + o] : b2[i*HD + o];
        PT[idx] = f2bf(v);
        return;
    }
    idx -= SEG_PT;
    if(idx < SEG_WIH){ WihB[idx] = f2bf(w_ih[idx]); return; }
    idx -= SEG_WIH;
    if(idx < SEG_WHH){ WhhB[idx] = f2bf(w_hh[idx]); return; }
    idx -= SEG_WHH;
    if(idx < SEG_WR){ WrB[idx] = f2bf(Wroot[idx]); return; }
    idx -= SEG_WR;
    if(idx < nx) Abf[idx] = f2bf(x[idx]);
}

// one kc-row of 4 MFMA column-tiles into 4 accumulators (global-read path, bias row)
static __device__ __forceinline__ void mfma_row(const u16* __restrict__ Pb,
        int r, int g, bf16x8 a0, bf16x8 a1, f32x4* acc){
    #pragma unroll
    for(int cb = 0; cb < 4; cb++){
        bf16x8 b0 = *(const bf16x8*)&Pb[(cb*16 + r)*HD + g*8];
        bf16x8 b1 = *(const bf16x8*)&Pb[(cb*16 + r)*HD + 32 + g*8];
        acc[cb] = __builtin_amdgcn_mfma_f32_16x16x32_bf16(a0, b0, acc[cb], 0,0,0);
        acc[cb] = __builtin_amdgcn_mfma_f32_16x16x32_bf16(a1, b1, acc[cb], 0,0,0);
    }
}

// Kernel A (LDS-staged): block of 4 waves shares one 32 KB B-panel (Q = 4 kc rows),
// staged ONCE into LDS with XOR slot-swizzle, then MFMAs feed from ds_read_b128.
// NEW Mt layout (quad-pair interleaved): u128 unit at Mt[Qp*N*512 + node*512 + o*8]
// holds kc 8Qp..8Qp+7; block Q writes its u64 into half (Q&1).
// grid (17, N/64): Q<16 compute (Q==0 also bias row -> Mb); Q==16 blocks zero agg.
__global__ __launch_bounds__(256) void k_gemmA4(
        const u16* __restrict__ Abf, const u16* __restrict__ PT,
        u16* __restrict__ Mt, float* __restrict__ Mb, float* __restrict__ agg, int N){
    __shared__ u16 sP[4*HD*HD];       // 32 KB
    int t = threadIdx.x;
    int Q = blockIdx.x;               // 0..16
    if(Q == 16){                      // zero agg: N*HD floats via float4
        int stride = gridDim.y * 256;
        f32x4 z = (f32x4){0.f,0.f,0.f,0.f};
        for(int i = blockIdx.y*256 + t; i < N*HD/4; i += stride)
            *(f32x4*)&agg[i*4] = z;
        return;
    }
    int w = t >> 6, lane = t & 63;
    int r = lane & 15, g = lane >> 4;
    int n0 = (blockIdx.y * 4 + w) * 16;
    size_t NP = (size_t)N * 512;      // u16 units per quad-pair plane
    int Qp = Q >> 1, half = Q & 1;

    bf16x8 a0 = *(const bf16x8*)&Abf[(size_t)(n0 + r)*HD + g*8];
    bf16x8 a1 = *(const bf16x8*)&Abf[(size_t)(n0 + r)*HD + 32 + g*8];

    {
        const uint4* src = (const uint4*)(PT + (size_t)(Q*4)*HD*HD); // 2048 chunks
        uint4 tmp0 = src[0*256 + t], tmp1 = src[1*256 + t],
              tmp2 = src[2*256 + t], tmp3 = src[3*256 + t],
              tmp4 = src[4*256 + t], tmp5 = src[5*256 + t],
              tmp6 = src[6*256 + t], tmp7 = src[7*256 + t];
        #define STG(rd, val) { int idx = (rd)*256 + t; int row = idx >> 3, sl = idx & 7; \
            *(uint4*)((char*)sP + row*128 + ((sl ^ (row&7))<<4)) = (val); }
        STG(0, tmp0) STG(1, tmp1) STG(2, tmp2) STG(3, tmp3)
        STG(4, tmp4) STG(5, tmp5) STG(6, tmp6) STG(7, tmp7)
        #undef STG
    }
    __syncthreads();

    f32x4 acc0[4], acc1[4], acc2[4], acc3[4];
    #pragma unroll
    for(int cb = 0; cb < 4; cb++){
        acc0[cb] = (f32x4){0.f,0.f,0.f,0.f};
        acc1[cb] = (f32x4){0.f,0.f,0.f,0.f};
        acc2[cb] = (f32x4){0.f,0.f,0.f,0.f};
        acc3[cb] = (f32x4){0.f,0.f,0.f,0.f};
    }
    #define LDB(j, cb, ks) (*(const bf16x8*)((const char*)sP + \
        ((j)*64 + (cb)*16 + r)*128 + ((((ks)*4 + g) ^ (((cb)*16 + r)&7))<<4)))
    #pragma unroll
    for(int cb = 0; cb < 4; cb++){
        acc0[cb] = __builtin_amdgcn_mfma_f32_16x16x32_bf16(a0, LDB(0,cb,0), acc0[cb], 0,0,0);
        acc0[cb] = __builtin_amdgcn_mfma_f32_16x16x32_bf16(a1, LDB(0,cb,1), acc0[cb], 0,0,0);
        acc1[cb] = __builtin_amdgcn_mfma_f32_16x16x32_bf16(a0, LDB(1,cb,0), acc1[cb], 0,0,0);
        acc1[cb] = __builtin_amdgcn_mfma_f32_16x16x32_bf16(a1, LDB(1,cb,1), acc1[cb], 0,0,0);
        acc2[cb] = __builtin_amdgcn_mfma_f32_16x16x32_bf16(a0, LDB(2,cb,0), acc2[cb], 0,0,0);
        acc2[cb] = __builtin_amdgcn_mfma_f32_16x16x32_bf16(a1, LDB(2,cb,1), acc2[cb], 0,0,0);
        acc3[cb] = __builtin_amdgcn_mfma_f32_16x16x32_bf16(a0, LDB(3,cb,0), acc3[cb], 0,0,0);
        acc3[cb] = __builtin_amdgcn_mfma_f32_16x16x32_bf16(a1, LDB(3,cb,1), acc3[cb], 0,0,0);
    }
    #undef LDB
    #pragma unroll
    for(int cb = 0; cb < 4; cb++){
        int o = cb*16 + r;
        #pragma unroll
        for(int reg = 0; reg < 4; reg++){
            int node = n0 + 4*g + reg;
            u64 v = (u64)pk2(acc0[cb][reg], acc1[cb][reg])
                  | ((u64)pk2(acc2[cb][reg], acc3[cb][reg]) << 32);
            *(u64*)&Mt[(size_t)Qp*NP + (size_t)node*512 + (size_t)o*8 + half*4] = v;
        }
    }
    if(Q == 0){                       // bias row kc = 64 -> Mb (f32), global-read path
        f32x4 accB[4];
        #pragma unroll
        for(int cb = 0; cb < 4; cb++) accB[cb] = (f32x4){0.f,0.f,0.f,0.f};
        mfma_row(PT + (size_t)64*HD*HD, r, g, a0, a1, accB);
        #pragma unroll
        for(int cb = 0; cb < 4; cb++)
            #pragma unroll
            for(int reg = 0; reg < 4; reg++)
                Mb[(size_t)(n0 + 4*g + reg)*HD + cb*16 + r] = accB[cb][reg];
    }
}

// Kernel B: wave per src node, B-frags from quad-pair Mt via ONE 16B load each
// (u128 = exactly one bf16x8 fragment), MFMA per 16-edge tile, atomic scatter.
// grid N/4, block 256.
__global__ __launch_bounds__(256) void k_msgB(
        const u16* __restrict__ Mt, const float* __restrict__ Mb,
        const u16* __restrict__ h1E, const int* __restrict__ rowptr,
        const int* __restrict__ dstE, int E, float* __restrict__ agg, int N){
    int t = threadIdx.x;
    int w = t >> 6, lane = t & 63;
    int r = lane & 15, g = lane >> 4;
    int s = blockIdx.x * 4 + w;
    int beg = rowptr[s], end = rowptr[s+1];
    if(beg == end) return;
    size_t NP = (size_t)N * 512;

    const u16* Mn = Mt + (size_t)s*512;
    bf16x8 sB[4][2];
    float bval[4];
    #pragma unroll
    for(int cb = 0; cb < 4; cb++){
        int o = cb*16 + r;
        #pragma unroll
        for(int ks = 0; ks < 2; ks++){
            int Qp = ks*4 + g;        // frag kc = ks*32+g*8+j = 8*Qp+j  -> one u128
            sB[cb][ks] = *(const bf16x8*)&Mn[(size_t)Qp*NP + (size_t)o*8];
        }
        bval[cb] = Mb[(size_t)s*HD + o];
    }
    for(int p0 = beg; p0 < end; p0 += 16){
        int p = p0 + r;
        int pc = p < E ? p : E-1;
        bf16x8 h0 = *(const bf16x8*)&h1E[(size_t)pc*HD + g*8];
        bf16x8 h1 = *(const bf16x8*)&h1E[(size_t)pc*HD + 32 + g*8];
        f32x4 acc2[4];
        #pragma unroll
        for(int cb = 0; cb < 4; cb++){
            acc2[cb] = (f32x4){0.f,0.f,0.f,0.f};
            acc2[cb] = __builtin_amdgcn_mfma_f32_16x16x32_bf16(h0, sB[cb][0], acc2[cb], 0,0,0);
            acc2[cb] = __builtin_amdgcn_mfma_f32_16x16x32_bf16(h1, sB[cb][1], acc2[cb], 0,0,0);
        }
        int dq[4];
        #pragma unroll
        for(int reg = 0; reg < 4; reg++){
            int q = p0 + 4*g + reg;
            dq[reg] = (q < end) ? dstE[q] : -1;
        }
        #pragma unroll
        for(int cb = 0; cb < 4; cb++)
            #pragma unroll
            for(int reg = 0; reg < 4; reg++)
                if(dq[reg] >= 0)
                    atomicAdd(&agg[(size_t)dq[reg]*HD + cb*16 + r],
                              acc2[cb][reg] + bval[cb]);
    }
}

// MFMA m+GRU: 16 nodes/block, 256 thr (4 waves). ROOT/GI/GH via mfma_16x16x32_bf16.
#define GSTR 201
__global__ __launch_bounds__(256) void k_mgru2(
        const float* __restrict__ agg, const float* __restrict__ countsf,
        const float* __restrict__ state, const u16* __restrict__ Abf,
        const u16* __restrict__ WrB,  const u16* __restrict__ WihB,
        const u16* __restrict__ WhhB, const float* __restrict__ bconv,
        const float* __restrict__ b_ih, const float* __restrict__ b_hh,
        float* __restrict__ hnew, u16* __restrict__ AbfN){
    __shared__ u16   s_mbf[16*72];            // m bf16, row stride 72
    __shared__ float s_gi[16*GSTR];
    __shared__ float s_gh[16*GSTR];
    int t = threadIdx.x;
    int w = t >> 6, lane = t & 63;
    int r = lane & 15, g = lane >> 4;
    int n0 = blockIdx.x * 16;

    bf16x8 afr0 = *(const bf16x8*)&Abf[(size_t)(n0 + r)*HD + g*8];
    bf16x8 afr1 = *(const bf16x8*)&Abf[(size_t)(n0 + r)*HD + 32 + g*8];

    {
        float bc = bconv[w*16 + r];
        f32x4 accR = (f32x4){bc, bc, bc, bc};
        bf16x8 b0 = *(const bf16x8*)&WrB[(size_t)(w*16 + r)*HD + g*8];
        bf16x8 b1 = *(const bf16x8*)&WrB[(size_t)(w*16 + r)*HD + 32 + g*8];
        accR = __builtin_amdgcn_mfma_f32_16x16x32_bf16(afr0, b0, accR, 0,0,0);
        accR = __builtin_amdgcn_mfma_f32_16x16x32_bf16(afr1, b1, accR, 0,0,0);
        #pragma unroll
        for(int reg = 0; reg < 4; reg++){
            int row = 4*g + reg;
            float cnt = countsf[n0 + row];
            float m = agg[(size_t)(n0 + row)*HD + w*16 + r] / cnt + accR[reg];
            s_mbf[row*72 + w*16 + r] = f2bf(m > 0.f ? m : 0.f);
        }
    }
    __syncthreads();

    bf16x8 am0 = *(const bf16x8*)&s_mbf[r*72 + g*8];
    bf16x8 am1 = *(const bf16x8*)&s_mbf[r*72 + 32 + g*8];

    #pragma unroll
    for(int j = 0; j < 3; j++){
        int cb = w + 4*j;
        int col = cb*16 + r;
        float bi = b_ih[col];
        f32x4 acc = (f32x4){bi, bi, bi, bi};
        bf16x8 b0 = *(const bf16x8*)&WihB[(size_t)col*HD + g*8];
        bf16x8 b1 = *(const bf16x8*)&WihB[(size_t)col*HD + 32 + g*8];
        acc = __builtin_amdgcn_mfma_f32_16x16x32_bf16(am0, b0, acc, 0,0,0);
        acc = __builtin_amdgcn_mfma_f32_16x16x32_bf16(am1, b1, acc, 0,0,0);
        #pragma unroll
        for(int reg = 0; reg < 4; reg++)
            s_gi[(4*g + reg)*GSTR + col] = acc[reg];
    }
    #pragma unroll
    for(int j = 0; j < 3; j++){
        int cb = w + 4*j;
        int col = cb*16 + r;
        float bh = b_hh[col];
        f32x4 acc = (f32x4){bh, bh, bh, bh};
        bf16x8 b0 = *(const bf16x8*)&WhhB[(size_t)col*HD + g*8];
        bf16x8 b1 = *(const bf16x8*)&WhhB[(size_t)col*HD + 32 + g*8];
        acc = __builtin_amdgcn_mfma_f32_16x16x32_bf16(afr0, b0, acc, 0,0,0);
        acc = __builtin_amdgcn_mfma_f32_16x16x32_bf16(afr1, b1, acc, 0,0,0);
        #pragma unroll
        for(int reg = 0; reg < 4; reg++)
            s_gh[(4*g + reg)*GSTR + col] = acc[reg];
    }
    __syncthreads();

    #pragma unroll
    for(int q = 0; q < 4; q++){
        int idx = t + q*256;
        int nl = idx >> 6, o = idx & 63;
        const float* gi = s_gi + nl*GSTR;
        const float* gh = s_gh + nl*GSTR;
        float rr  = 1.f/(1.f + __expf(-(gi[o]      + gh[o])));
        float zz  = 1.f/(1.f + __expf(-(gi[64+o]   + gh[64+o])));
        float nnv = tanhf(gi[128+o] + rr*gh[128+o]);
        float xo = state[(size_t)(n0+nl)*HD + o];
        float hh = (1.f - zz)*nnv + zz*xo;
        hnew[(size_t)(n0+nl)*HD + o] = hh;
        AbfN[(size_t)(n0+nl)*HD + o] = f2bf(hh);
    }
}

extern "C" void kernel_launch(void* const* d_in, const int* in_sizes, int n_in,
                              void* d_out, int out_size, void* d_ws, size_t ws_size,
                              hipStream_t stream){
    const float* x     = (const float*)d_in[0];
    const float* ea    = (const float*)d_in[1];
    const float* W1    = (const float*)d_in[2];
    const float* b1    = (const float*)d_in[3];
    const float* W2    = (const float*)d_in[4];
    const float* b2    = (const float*)d_in[5];
    const float* Wroot = (const float*)d_in[6];
    const float* bconv = (const float*)d_in[7];
    const float* w_ih  = (const float*)d_in[8];
    const float* w_hh  = (const float*)d_in[9];
    const float* b_ih  = (const float*)d_in[10];
    const float* b_hh  = (const float*)d_in[11];
    const int*   eidx  = (const int*)d_in[12];
    int N = in_sizes[0] / HD;
    int E = in_sizes[1] / ED;
    const int* srcarr = eidx;
    const int* dstarr = eidx + E;

    char* w = (char*)d_ws;
    size_t off = 0;
    auto alloc = [&](size_t bytes)->char*{
        char* p = w + off; off = (off + bytes + 255) & ~(size_t)255; return p;
    };
    int*   deg_src = (int*)alloc((size_t)N*4);
    int*   deg_dst = (int*)alloc((size_t)N*4);
    int*   rowptr  = (int*)alloc((size_t)(N+1)*4);
    int*   cursor  = (int*)alloc((size_t)N*4);
    int*   elist   = (int*)alloc((size_t)E*4);
    int*   dstE    = (int*)alloc((size_t)E*4);
    float* countsf = (float*)alloc((size_t)N*4);
    u16*   h1E     = (u16*)alloc((size_t)E*HD*2);
    u16*   PT      = (u16*)alloc((size_t)65*HD*HD*2);
    u16*   Abf     = (u16*)alloc((size_t)N*HD*2);
    u16*   WihB    = (u16*)alloc((size_t)3*HD*HD*2);
    u16*   WhhB    = (u16*)alloc((size_t)3*HD*HD*2);
    u16*   WrB     = (u16*)alloc((size_t)HD*HD*2);
    float* agg     = (float*)alloc((size_t)N*HD*4);
    float* stA     = (float*)alloc((size_t)N*HD*4);
    float* stB     = (float*)alloc((size_t)N*HD*4);
    float* Mb      = (float*)alloc((size_t)N*HD*4);
    u16*   Mt      = (u16*)alloc((size_t)N*4096*2);   // 64 MB, quad-pair frag-native M

    // ---- precompute ----
    hipLaunchKernelGGL(k_zero2, dim3((N+255)/256), dim3(256), 0, stream, deg_src, deg_dst, N);
    hipLaunchKernelGGL(k_deg,   dim3((E+255)/256), dim3(256), 0, stream, srcarr, dstarr, E, deg_src, deg_dst);
    hipLaunchKernelGGL(k_scan,  dim3(1), dim3(1024), 0, stream, deg_src, deg_dst, N, rowptr, cursor, countsf);
    hipLaunchKernelGGL(k_fill,  dim3((E+255)/256), dim3(256), 0, stream, srcarr, E, cursor, elist);
    hipLaunchKernelGGL(k_h1E,   dim3((E+3)/4), dim3(256), 0, stream, ea, W1, b1, elist, dstarr, E, h1E, dstE);
    int prep_total = SEG_PT + SEG_WIH + SEG_WHH + SEG_WR + N*HD;
    hipLaunchKernelGGL(k_prep,  dim3((prep_total+255)/256), dim3(256), 0, stream,
                       W2, b2, w_ih, w_hh, Wroot, x, PT, WihB, WhhB, WrB, Abf, N*HD);

    // ---- 3 message-passing + GRU iterations ----
    const float* state = x;
    for(int it = 0; it < 3; ++it){
        hipLaunchKernelGGL(k_gemmA4, dim3(17, N/64), dim3(256), 0, stream, Abf, PT, Mt, Mb, agg, N);
        hipLaunchKernelGGL(k_msgB,  dim3(N/4), dim3(256), 0, stream,
                           Mt, Mb, h1E, rowptr, dstE, E, agg, N);
        float* outp = (it == 2) ? (float*)d_out : ((it == 0) ? stA : stB);
        hipLaunchKernelGGL(k_mgru2, dim3(N/16), dim3(256), 0, stream,
                           agg, countsf, state, Abf, WrB, WihB, WhhB,
                           bconv, b_ih, b_hh, outp, Abf);
        state = outp;
    }
}

// Round 17
// 180.469 us; speedup vs baseline: 1.2161x; 1.2161x over previous
//
#include <hip/hip_runtime.h>

#define HD 64
#define ED 16

typedef __bf16 bf16x8 __attribute__((ext_vector_type(8)));
typedef float  f32x4  __attribute__((ext_vector_type(4)));
typedef unsigned int u32;
typedef unsigned long long u64;
typedef unsigned short u16;

static inline __device__ float bf2f(u16 u){
    union { u32 i; float f; } v; v.i = ((u32)u) << 16; return v.f;
}
static inline __device__ u16 f2bf(float f){
    union { u32 i; float f; } v; v.f = f;
    u32 r = v.i + 0x7FFF + ((v.i >> 16) & 1);
    return (u16)(r >> 16);
}
static inline __device__ u32 pk2(float a, float b){
    return (u32)f2bf(a) | ((u32)f2bf(b) << 16);
}

__global__ void k_zero2(int* a, int* b, int n){
    int i = blockIdx.x*blockDim.x + threadIdx.x;
    if(i < n){ a[i] = 0; b[i] = 0; }
}
__global__ void k_deg(const int* __restrict__ src, const int* __restrict__ dst, int E,
                      int* __restrict__ degs, int* __restrict__ degd){
    int e = blockIdx.x*blockDim.x + threadIdx.x;
    if(e < E){ atomicAdd(&degs[src[e]], 1); atomicAdd(&degd[dst[e]], 1); }
}

// single-block scan: deg_src -> rowptr/cursor ; deg_dst -> countsf = max(deg,1)
__global__ void k_scan(const int* __restrict__ degs, const int* __restrict__ degd, int N,
                       int* __restrict__ rowptr, int* __restrict__ cursor, float* __restrict__ countsf){
    __shared__ int part[1024];
    int tid = threadIdx.x;
    int PER = (N + 1023) >> 10;
    int base = tid * PER;
    int local[16];
    int s = 0;
    for(int j = 0; j < PER; j++){
        int idx = base + j;
        int v = (idx < N) ? degs[idx] : 0;
        local[j] = s; s += v;
    }
    part[tid] = s;
    __syncthreads();
    for(int off = 1; off < 1024; off <<= 1){
        int v = (tid >= off) ? part[tid - off] : 0;
        __syncthreads();
        part[tid] += v;
        __syncthreads();
    }
    int prev = (tid == 0) ? 0 : part[tid - 1];
    for(int j = 0; j < PER; j++){
        int idx = base + j;
        if(idx < N){
            int r = prev + local[j];
            rowptr[idx] = r; cursor[idx] = r;
            int dd = degd[idx];
            countsf[idx] = (dd > 0) ? (float)dd : 1.0f;
        }
    }
    if(tid == 1023) rowptr[N] = prev + s;
}

__global__ void k_fill(const int* __restrict__ src, int E, int* __restrict__ cursor, int* __restrict__ elist){
    int e = blockIdx.x*blockDim.x + threadIdx.x;
    if(e < E){ int p = atomicAdd(&cursor[src[e]], 1); elist[p] = e; }
}

// h1E[p] = bf16(relu(edge_attr[elist[p]] @ W1 + b1)) in CSR order; dstE[p] = dst[elist[p]]
__global__ void k_h1E(const float* __restrict__ ea, const float* __restrict__ W1,
                      const float* __restrict__ b1, const int* __restrict__ elist,
                      const int* __restrict__ dstarr, int E,
                      u16* __restrict__ h1E, int* __restrict__ dstE){
    __shared__ float s_ea[4][ED];
    __shared__ int s_e[4];
    int t = threadIdx.x;              // 256
    int o = t & 63, el = t >> 6;
    int p = blockIdx.x*4 + el;
    if(t < 4){
        int pp = blockIdx.x*4 + t;
        s_e[t] = (pp < E) ? elist[pp] : 0;
    }
    __syncthreads();
    if(t < 4*ED){
        int pe = t/ED;
        s_ea[pe][t%ED] = ea[(size_t)s_e[pe]*ED + t%ED];
    }
    __syncthreads();
    if(p < E){
        float acc = b1[o];
        #pragma unroll
        for(int k = 0; k < ED; k++) acc += s_ea[el][k] * W1[k*HD + o];
        h1E[(size_t)p*HD + o] = f2bf(acc > 0.f ? acc : 0.f);
        if(o == 0) dstE[p] = dstarr[s_e[el]];
    }
}

// merged one-time conversions: PT (from W2+b2), WihB, WhhB, WrB, Abf(from x)
#define SEG_PT   (65*HD*HD)          // 266240
#define SEG_WIH  (3*HD*HD)           // 12288
#define SEG_WHH  (3*HD*HD)
#define SEG_WR   (HD*HD)
__global__ void k_prep(const float* __restrict__ W2, const float* __restrict__ b2,
                       const float* __restrict__ w_ih, const float* __restrict__ w_hh,
                       const float* __restrict__ Wroot, const float* __restrict__ x,
                       u16* __restrict__ PT, u16* __restrict__ WihB, u16* __restrict__ WhhB,
                       u16* __restrict__ WrB, u16* __restrict__ Abf, int nx){
    int idx = blockIdx.x*blockDim.x + threadIdx.x;
    if(idx < SEG_PT){
        int c = idx / HD, i = idx % HD;
        int kc = c >> 6, o = c & 63;
        float v = (kc < HD) ? W2[(size_t)kc*(HD*HD) + i*HD + o] : b2[i*HD + o];
        PT[idx] = f2bf(v);
        return;
    }
    idx -= SEG_PT;
    if(idx < SEG_WIH){ WihB[idx] = f2bf(w_ih[idx]); return; }
    idx -= SEG_WIH;
    if(idx < SEG_WHH){ WhhB[idx] = f2bf(w_hh[idx]); return; }
    idx -= SEG_WHH;
    if(idx < SEG_WR){ WrB[idx] = f2bf(Wroot[idx]); return; }
    idx -= SEG_WR;
    if(idx < nx) Abf[idx] = f2bf(x[idx]);
}

// one kc-row of 4 MFMA column-tiles into 4 accumulators (global-read path, bias row)
static __device__ __forceinline__ void mfma_row(const u16* __restrict__ Pb,
        int r, int g, bf16x8 a0, bf16x8 a1, f32x4* acc){
    #pragma unroll
    for(int cb = 0; cb < 4; cb++){
        bf16x8 b0 = *(const bf16x8*)&Pb[(cb*16 + r)*HD + g*8];
        bf16x8 b1 = *(const bf16x8*)&Pb[(cb*16 + r)*HD + 32 + g*8];
        acc[cb] = __builtin_amdgcn_mfma_f32_16x16x32_bf16(a0, b0, acc[cb], 0,0,0);
        acc[cb] = __builtin_amdgcn_mfma_f32_16x16x32_bf16(a1, b1, acc[cb], 0,0,0);
    }
}

// Kernel A (LDS-staged): block of 4 waves shares one 32 KB B-panel (Q = 4 kc rows),
// staged ONCE into LDS with XOR slot-swizzle, then MFMAs feed from ds_read_b128.
// Mt plane-major: u64 unit at Mt[Q*N*256 + node*256 + o*4] (u16 units).
// PLAIN (cacheable) stores: M spills L2->L3; msgB reads ride Infinity Cache.
// grid (17, N/64): Q<16 compute (Q==0 also bias row -> Mb); Q==16 blocks zero agg.
__global__ __launch_bounds__(256) void k_gemmA4(
        const u16* __restrict__ Abf, const u16* __restrict__ PT,
        u16* __restrict__ Mt, float* __restrict__ Mb, float* __restrict__ agg, int N){
    __shared__ u16 sP[4*HD*HD];       // 32 KB
    int t = threadIdx.x;
    int Q = blockIdx.x;               // 0..16
    if(Q == 16){                      // zero agg: N*HD floats via float4
        int stride = gridDim.y * 256;
        f32x4 z = (f32x4){0.f,0.f,0.f,0.f};
        for(int i = blockIdx.y*256 + t; i < N*HD/4; i += stride)
            *(f32x4*)&agg[i*4] = z;
        return;
    }
    int w = t >> 6, lane = t & 63;
    int r = lane & 15, g = lane >> 4;
    int n0 = (blockIdx.y * 4 + w) * 16;
    size_t NQ = (size_t)N * 256;      // u16 units per plane

    bf16x8 a0 = *(const bf16x8*)&Abf[(size_t)(n0 + r)*HD + g*8];
    bf16x8 a1 = *(const bf16x8*)&Abf[(size_t)(n0 + r)*HD + 32 + g*8];

    {
        const uint4* src = (const uint4*)(PT + (size_t)(Q*4)*HD*HD); // 2048 chunks
        uint4 tmp0 = src[0*256 + t], tmp1 = src[1*256 + t],
              tmp2 = src[2*256 + t], tmp3 = src[3*256 + t],
              tmp4 = src[4*256 + t], tmp5 = src[5*256 + t],
              tmp6 = src[6*256 + t], tmp7 = src[7*256 + t];
        #define STG(rd, val) { int idx = (rd)*256 + t; int row = idx >> 3, sl = idx & 7; \
            *(uint4*)((char*)sP + row*128 + ((sl ^ (row&7))<<4)) = (val); }
        STG(0, tmp0) STG(1, tmp1) STG(2, tmp2) STG(3, tmp3)
        STG(4, tmp4) STG(5, tmp5) STG(6, tmp6) STG(7, tmp7)
        #undef STG
    }
    __syncthreads();

    f32x4 acc0[4], acc1[4], acc2[4], acc3[4];
    #pragma unroll
    for(int cb = 0; cb < 4; cb++){
        acc0[cb] = (f32x4){0.f,0.f,0.f,0.f};
        acc1[cb] = (f32x4){0.f,0.f,0.f,0.f};
        acc2[cb] = (f32x4){0.f,0.f,0.f,0.f};
        acc3[cb] = (f32x4){0.f,0.f,0.f,0.f};
    }
    #define LDB(j, cb, ks) (*(const bf16x8*)((const char*)sP + \
        ((j)*64 + (cb)*16 + r)*128 + ((((ks)*4 + g) ^ (((cb)*16 + r)&7))<<4)))
    #pragma unroll
    for(int cb = 0; cb < 4; cb++){
        acc0[cb] = __builtin_amdgcn_mfma_f32_16x16x32_bf16(a0, LDB(0,cb,0), acc0[cb], 0,0,0);
        acc0[cb] = __builtin_amdgcn_mfma_f32_16x16x32_bf16(a1, LDB(0,cb,1), acc0[cb], 0,0,0);
        acc1[cb] = __builtin_amdgcn_mfma_f32_16x16x32_bf16(a0, LDB(1,cb,0), acc1[cb], 0,0,0);
        acc1[cb] = __builtin_amdgcn_mfma_f32_16x16x32_bf16(a1, LDB(1,cb,1), acc1[cb], 0,0,0);
        acc2[cb] = __builtin_amdgcn_mfma_f32_16x16x32_bf16(a0, LDB(2,cb,0), acc2[cb], 0,0,0);
        acc2[cb] = __builtin_amdgcn_mfma_f32_16x16x32_bf16(a1, LDB(2,cb,1), acc2[cb], 0,0,0);
        acc3[cb] = __builtin_amdgcn_mfma_f32_16x16x32_bf16(a0, LDB(3,cb,0), acc3[cb], 0,0,0);
        acc3[cb] = __builtin_amdgcn_mfma_f32_16x16x32_bf16(a1, LDB(3,cb,1), acc3[cb], 0,0,0);
    }
    #undef LDB
    #pragma unroll
    for(int cb = 0; cb < 4; cb++){
        int o = cb*16 + r;
        #pragma unroll
        for(int reg = 0; reg < 4; reg++){
            int node = n0 + 4*g + reg;
            u64 v = (u64)pk2(acc0[cb][reg], acc1[cb][reg])
                  | ((u64)pk2(acc2[cb][reg], acc3[cb][reg]) << 32);
            *(u64*)&Mt[(size_t)Q*NQ + (size_t)node*256 + (size_t)o*4] = v;
        }
    }
    if(Q == 0){                       // bias row kc = 64 -> Mb (f32), global-read path
        f32x4 accB[4];
        #pragma unroll
        for(int cb = 0; cb < 4; cb++) accB[cb] = (f32x4){0.f,0.f,0.f,0.f};
        mfma_row(PT + (size_t)64*HD*HD, r, g, a0, a1, accB);
        #pragma unroll
        for(int cb = 0; cb < 4; cb++)
            #pragma unroll
            for(int reg = 0; reg < 4; reg++)
                Mb[(size_t)(n0 + 4*g + reg)*HD + cb*16 + r] = accB[cb][reg];
    }
}

// Kernel B: wave per src node, B-frags from plane-major Mt via 2x 8B NONTEMPORAL
// loads per (cb,ks) (single-use stream; keep L2 free for agg/h1E), MFMA per
// 16-edge tile, atomic scatter into agg. grid N/4, block 256.
__global__ __launch_bounds__(256) void k_msgB(
        const u16* __restrict__ Mt, const float* __restrict__ Mb,
        const u16* __restrict__ h1E, const int* __restrict__ rowptr,
        const int* __restrict__ dstE, int E, float* __restrict__ agg, int N){
    int t = threadIdx.x;
    int w = t >> 6, lane = t & 63;
    int r = lane & 15, g = lane >> 4;
    int s = blockIdx.x * 4 + w;
    int beg = rowptr[s], end = rowptr[s+1];
    if(beg == end) return;
    size_t NQ = (size_t)N * 256;

    const u16* Mn = Mt + (size_t)s*256;
    bf16x8 sB[4][2];
    float bval[4];
    #pragma unroll
    for(int cb = 0; cb < 4; cb++){
        int o = cb*16 + r;
        #pragma unroll
        for(int ks = 0; ks < 2; ks++){
            int Qa = ks*8 + 2*g;      // frag k = g*8+j -> kc = ks*32+g*8+j -> quads Qa,Qa+1
            u64 lo = __builtin_nontemporal_load((const u64*)&Mn[(size_t)Qa*NQ + o*4]);
            u64 hi = __builtin_nontemporal_load((const u64*)&Mn[(size_t)(Qa+1)*NQ + o*4]);
            union { u64 q[2]; bf16x8 v; } u;
            u.q[0] = lo; u.q[1] = hi;
            sB[cb][ks] = u.v;
        }
        bval[cb] = Mb[(size_t)s*HD + o];
    }
    for(int p0 = beg; p0 < end; p0 += 16){
        int p = p0 + r;
        int pc = p < E ? p : E-1;
        bf16x8 h0 = *(const bf16x8*)&h1E[(size_t)pc*HD + g*8];
        bf16x8 h1 = *(const bf16x8*)&h1E[(size_t)pc*HD + 32 + g*8];
        f32x4 acc2[4];
        #pragma unroll
        for(int cb = 0; cb < 4; cb++){
            acc2[cb] = (f32x4){0.f,0.f,0.f,0.f};
            acc2[cb] = __builtin_amdgcn_mfma_f32_16x16x32_bf16(h0, sB[cb][0], acc2[cb], 0,0,0);
            acc2[cb] = __builtin_amdgcn_mfma_f32_16x16x32_bf16(h1, sB[cb][1], acc2[cb], 0,0,0);
        }
        int dq[4];
        #pragma unroll
        for(int reg = 0; reg < 4; reg++){
            int q = p0 + 4*g + reg;
            dq[reg] = (q < end) ? dstE[q] : -1;
        }
        #pragma unroll
        for(int cb = 0; cb < 4; cb++)
            #pragma unroll
            for(int reg = 0; reg < 4; reg++)
                if(dq[reg] >= 0)
                    atomicAdd(&agg[(size_t)dq[reg]*HD + cb*16 + r],
                              acc2[cb][reg] + bval[cb]);
    }
}

// MFMA m+GRU: 16 nodes/block, 256 thr (4 waves). ROOT/GI/GH via mfma_16x16x32_bf16.
#define GSTR 201
__global__ __launch_bounds__(256) void k_mgru2(
        const float* __restrict__ agg, const float* __restrict__ countsf,
        const float* __restrict__ state, const u16* __restrict__ Abf,
        const u16* __restrict__ WrB,  const u16* __restrict__ WihB,
        const u16* __restrict__ WhhB, const float* __restrict__ bconv,
        const float* __restrict__ b_ih, const float* __restrict__ b_hh,
        float* __restrict__ hnew, u16* __restrict__ AbfN){
    __shared__ u16   s_mbf[16*72];            // m bf16, row stride 72
    __shared__ float s_gi[16*GSTR];
    __shared__ float s_gh[16*GSTR];
    int t = threadIdx.x;
    int w = t >> 6, lane = t & 63;
    int r = lane & 15, g = lane >> 4;
    int n0 = blockIdx.x * 16;

    bf16x8 afr0 = *(const bf16x8*)&Abf[(size_t)(n0 + r)*HD + g*8];
    bf16x8 afr1 = *(const bf16x8*)&Abf[(size_t)(n0 + r)*HD + 32 + g*8];

    {
        float bc = bconv[w*16 + r];
        f32x4 accR = (f32x4){bc, bc, bc, bc};
        bf16x8 b0 = *(const bf16x8*)&WrB[(size_t)(w*16 + r)*HD + g*8];
        bf16x8 b1 = *(const bf16x8*)&WrB[(size_t)(w*16 + r)*HD + 32 + g*8];
        accR = __builtin_amdgcn_mfma_f32_16x16x32_bf16(afr0, b0, accR, 0,0,0);
        accR = __builtin_amdgcn_mfma_f32_16x16x32_bf16(afr1, b1, accR, 0,0,0);
        #pragma unroll
        for(int reg = 0; reg < 4; reg++){
            int row = 4*g + reg;
            float cnt = countsf[n0 + row];
            float m = agg[(size_t)(n0 + row)*HD + w*16 + r] / cnt + accR[reg];
            s_mbf[row*72 + w*16 + r] = f2bf(m > 0.f ? m : 0.f);
        }
    }
    __syncthreads();

    bf16x8 am0 = *(const bf16x8*)&s_mbf[r*72 + g*8];
    bf16x8 am1 = *(const bf16x8*)&s_mbf[r*72 + 32 + g*8];

    #pragma unroll
    for(int j = 0; j < 3; j++){
        int cb = w + 4*j;
        int col = cb*16 + r;
        float bi = b_ih[col];
        f32x4 acc = (f32x4){bi, bi, bi, bi};
        bf16x8 b0 = *(const bf16x8*)&WihB[(size_t)col*HD + g*8];
        bf16x8 b1 = *(const bf16x8*)&WihB[(size_t)col*HD + 32 + g*8];
        acc = __builtin_amdgcn_mfma_f32_16x16x32_bf16(am0, b0, acc, 0,0,0);
        acc = __builtin_amdgcn_mfma_f32_16x16x32_bf16(am1, b1, acc, 0,0,0);
        #pragma unroll
        for(int reg = 0; reg < 4; reg++)
            s_gi[(4*g + reg)*GSTR + col] = acc[reg];
    }
    #pragma unroll
    for(int j = 0; j < 3; j++){
        int cb = w + 4*j;
        int col = cb*16 + r;
        float bh = b_hh[col];
        f32x4 acc = (f32x4){bh, bh, bh, bh};
        bf16x8 b0 = *(const bf16x8*)&WhhB[(size_t)col*HD + g*8];
        bf16x8 b1 = *(const bf16x8*)&WhhB[(size_t)col*HD + 32 + g*8];
        acc = __builtin_amdgcn_mfma_f32_16x16x32_bf16(afr0, b0, acc, 0,0,0);
        acc = __builtin_amdgcn_mfma_f32_16x16x32_bf16(afr1, b1, acc, 0,0,0);
        #pragma unroll
        for(int reg = 0; reg < 4; reg++)
            s_gh[(4*g + reg)*GSTR + col] = acc[reg];
    }
    __syncthreads();

    #pragma unroll
    for(int q = 0; q < 4; q++){
        int idx = t + q*256;
        int nl = idx >> 6, o = idx & 63;
        const float* gi = s_gi + nl*GSTR;
        const float* gh = s_gh + nl*GSTR;
        float rr  = 1.f/(1.f + __expf(-(gi[o]      + gh[o])));
        float zz  = 1.f/(1.f + __expf(-(gi[64+o]   + gh[64+o])));
        float nnv = tanhf(gi[128+o] + rr*gh[128+o]);
        float xo = state[(size_t)(n0+nl)*HD + o];
        float hh = (1.f - zz)*nnv + zz*xo;
        hnew[(size_t)(n0+nl)*HD + o] = hh;
        AbfN[(size_t)(n0+nl)*HD + o] = f2bf(hh);
    }
}

extern "C" void kernel_launch(void* const* d_in, const int* in_sizes, int n_in,
                              void* d_out, int out_size, void* d_ws, size_t ws_size,
                              hipStream_t stream){
    const float* x     = (const float*)d_in[0];
    const float* ea    = (const float*)d_in[1];
    const float* W1    = (const float*)d_in[2];
    const float* b1    = (const float*)d_in[3];
    const float* W2    = (const float*)d_in[4];
    const float* b2    = (const float*)d_in[5];
    const float* Wroot = (const float*)d_in[6];
    const float* bconv = (const float*)d_in[7];
    const float* w_ih  = (const float*)d_in[8];
    const float* w_hh  = (const float*)d_in[9];
    const float* b_ih  = (const float*)d_in[10];
    const float* b_hh  = (const float*)d_in[11];
    const int*   eidx  = (const int*)d_in[12];
    int N = in_sizes[0] / HD;
    int E = in_sizes[1] / ED;
    const int* srcarr = eidx;
    const int* dstarr = eidx + E;

    char* w = (char*)d_ws;
    size_t off = 0;
    auto alloc = [&](size_t bytes)->char*{
        char* p = w + off; off = (off + bytes + 255) & ~(size_t)255; return p;
    };
    int*   deg_src = (int*)alloc((size_t)N*4);
    int*   deg_dst = (int*)alloc((size_t)N*4);
    int*   rowptr  = (int*)alloc((size_t)(N+1)*4);
    int*   cursor  = (int*)alloc((size_t)N*4);
    int*   elist   = (int*)alloc((size_t)E*4);
    int*   dstE    = (int*)alloc((size_t)E*4);
    float* countsf = (float*)alloc((size_t)N*4);
    u16*   h1E     = (u16*)alloc((size_t)E*HD*2);
    u16*   PT      = (u16*)alloc((size_t)65*HD*HD*2);
    u16*   Abf     = (u16*)alloc((size_t)N*HD*2);
    u16*   WihB    = (u16*)alloc((size_t)3*HD*HD*2);
    u16*   WhhB    = (u16*)alloc((size_t)3*HD*HD*2);
    u16*   WrB     = (u16*)alloc((size_t)HD*HD*2);
    float* agg     = (float*)alloc((size_t)N*HD*4);
    float* stA     = (float*)alloc((size_t)N*HD*4);
    float* stB     = (float*)alloc((size_t)N*HD*4);
    float* Mb      = (float*)alloc((size_t)N*HD*4);
    u16*   Mt      = (u16*)alloc((size_t)N*4096*2);   // 64 MB, plane-major frag-native M

    // ---- precompute ----
    hipLaunchKernelGGL(k_zero2, dim3((N+255)/256), dim3(256), 0, stream, deg_src, deg_dst, N);
    hipLaunchKernelGGL(k_deg,   dim3((E+255)/256), dim3(256), 0, stream, srcarr, dstarr, E, deg_src, deg_dst);
    hipLaunchKernelGGL(k_scan,  dim3(1), dim3(1024), 0, stream, deg_src, deg_dst, N, rowptr, cursor, countsf);
    hipLaunchKernelGGL(k_fill,  dim3((E+255)/256), dim3(256), 0, stream, srcarr, E, cursor, elist);
    hipLaunchKernelGGL(k_h1E,   dim3((E+3)/4), dim3(256), 0, stream, ea, W1, b1, elist, dstarr, E, h1E, dstE);
    int prep_total = SEG_PT + SEG_WIH + SEG_WHH + SEG_WR + N*HD;
    hipLaunchKernelGGL(k_prep,  dim3((prep_total+255)/256), dim3(256), 0, stream,
                       W2, b2, w_ih, w_hh, Wroot, x, PT, WihB, WhhB, WrB, Abf, N*HD);

    // ---- 3 message-passing + GRU iterations ----
    const float* state = x;
    for(int it = 0; it < 3; ++it){
        hipLaunchKernelGGL(k_gemmA4, dim3(17, N/64), dim3(256), 0, stream, Abf, PT, Mt, Mb, agg, N);
        hipLaunchKernelGGL(k_msgB,  dim3(N/4), dim3(256), 0, stream,
                           Mt, Mb, h1E, rowptr, dstE, E, agg, N);
        float* outp = (it == 2) ? (float*)d_out : ((it == 0) ? stA : stB);
        hipLaunchKernelGGL(k_mgru2, dim3(N/16), dim3(256), 0, stream,
                           agg, countsf, state, Abf, WrB, WihB, WhhB,
                           bconv, b_ih, b_hh, outp, Abf);
        state = outp;
    }
}